// Round 1
// baseline (125.558 us; speedup 1.0000x reference)
//
#include <hip/hip_runtime.h>

typedef __bf16 bf16x8 __attribute__((ext_vector_type(8)));
typedef float f32x4 __attribute__((ext_vector_type(4)));

#define T_SEQ 8192
#define NB 2
#define CDIM 1024
#define HDIM 64
#define NROWS (NB * T_SEQ)  // 16384

static __device__ __forceinline__ unsigned short f2b(float f) {
    union { float f; unsigned u; } a; a.f = f;
    unsigned r = a.u + 0x7FFFu + ((a.u >> 16) & 1u);   // RNE to bf16
    return (unsigned short)(r >> 16);
}

// ---------------------------------------------------------------------------
// Kernel 1: WT[m][n][k] = W_m[k][n] as bf16 bits.  m in {q,k,v}, n<64, k<1024.
// ---------------------------------------------------------------------------
__global__ __launch_bounds__(256) void wt_kernel(const float* __restrict__ Wq,
                                                 const float* __restrict__ Wk,
                                                 const float* __restrict__ Wv,
                                                 unsigned short* __restrict__ WT) {
    int idx = blockIdx.x * 256 + threadIdx.x;  // < 3*64*1024 = 196608
    int m   = idx >> 16;
    int rem = idx & 65535;
    int n = rem >> 10, k = rem & 1023;
    const float* W = (m == 0) ? Wq : (m == 1) ? Wk : Wv;
    WT[idx] = f2b(W[k * HDIM + n]);
}

// ---------------------------------------------------------------------------
// Kernel 2: fused QKV projection.  BM=32 rows, BN=192 (q|k|v), BK=64.
// 256 threads = 4 waves; wave w owns cols [w*48, w*48+48): acc[2][3] frags.
// ---------------------------------------------------------------------------
__global__ __launch_bounds__(256) void qkv_kernel(const float* __restrict__ x,
                                                  const unsigned short* __restrict__ WT,
                                                  float* __restrict__ q,
                                                  float* __restrict__ k,
                                                  float* __restrict__ v) {
    __shared__ unsigned short Al[32][72];    // 32 rows x 64 k, pad to 72 (144 B rows)
    __shared__ unsigned short Bl[192][72];   // 192 n-rows x 64 k (transposed W)

    int tid  = threadIdx.x;
    int lane = tid & 63;
    int w    = tid >> 6;
    int lr   = lane & 15, lg = lane >> 4;
    long row0 = (long)blockIdx.x * 32;

    f32x4 acc[2][3];
    #pragma unroll
    for (int mi = 0; mi < 2; ++mi)
        #pragma unroll
        for (int ni = 0; ni < 3; ++ni)
            acc[mi][ni] = (f32x4){0.f, 0.f, 0.f, 0.f};

    int ar = tid >> 3, aq = tid & 7;             // A staging: 8 threads per row
    const float* xr = x + (row0 + ar) * CDIM;

    for (int kt = 0; kt < CDIM; kt += 64) {
        // ---- stage A (x tile, f32 -> bf16) ----
        float4 f0 = ((const float4*)(xr + kt))[aq];      // cols 4*aq   .. +4
        float4 f1 = ((const float4*)(xr + kt))[aq + 8];  // cols 32+4*aq.. +4
        ushort4 u0, u1;
        u0.x = f2b(f0.x); u0.y = f2b(f0.y); u0.z = f2b(f0.z); u0.w = f2b(f0.w);
        u1.x = f2b(f1.x); u1.y = f2b(f1.y); u1.z = f2b(f1.z); u1.w = f2b(f1.w);
        *(ushort4*)&Al[ar][aq * 4]      = u0;
        *(ushort4*)&Al[ar][32 + aq * 4] = u1;

        // ---- stage B (WT tile, already bf16, already [n][k]) ----
        #pragma unroll
        for (int i = 0; i < 6; ++i) {
            int wi = tid + i * 256;           // < 1536
            int r = wi >> 3, ch = wi & 7;     // row n, 16B chunk
            uint4 val = *(const uint4*)(WT + r * CDIM + kt + ch * 8);
            *(uint4*)&Bl[r][ch * 8] = val;
        }
        __syncthreads();

        // ---- MFMA: 2 k-slices of 32 ----
        #pragma unroll
        for (int kk = 0; kk < 2; ++kk) {
            bf16x8 a0 = *(const bf16x8*)&Al[lr][kk * 32 + lg * 8];
            bf16x8 a1 = *(const bf16x8*)&Al[16 + lr][kk * 32 + lg * 8];
            bf16x8 b0 = *(const bf16x8*)&Bl[w * 48 + lr][kk * 32 + lg * 8];
            bf16x8 b1 = *(const bf16x8*)&Bl[w * 48 + 16 + lr][kk * 32 + lg * 8];
            bf16x8 b2 = *(const bf16x8*)&Bl[w * 48 + 32 + lr][kk * 32 + lg * 8];
            acc[0][0] = __builtin_amdgcn_mfma_f32_16x16x32_bf16(a0, b0, acc[0][0], 0, 0, 0);
            acc[1][0] = __builtin_amdgcn_mfma_f32_16x16x32_bf16(a1, b0, acc[1][0], 0, 0, 0);
            acc[0][1] = __builtin_amdgcn_mfma_f32_16x16x32_bf16(a0, b1, acc[0][1], 0, 0, 0);
            acc[1][1] = __builtin_amdgcn_mfma_f32_16x16x32_bf16(a1, b1, acc[1][1], 0, 0, 0);
            acc[0][2] = __builtin_amdgcn_mfma_f32_16x16x32_bf16(a0, b2, acc[0][2], 0, 0, 0);
            acc[1][2] = __builtin_amdgcn_mfma_f32_16x16x32_bf16(a1, b2, acc[1][2], 0, 0, 0);
        }
        __syncthreads();
    }

    // ---- epilogue: C/D layout col=lane&15, row=(lane>>4)*4 + j (measured) ----
    #pragma unroll
    for (int mi = 0; mi < 2; ++mi)
        #pragma unroll
        for (int ni = 0; ni < 3; ++ni) {
            int cg  = w * 48 + ni * 16 + lr;  // global col 0..191
            int mat = cg >> 6, cc = cg & 63;
            float* op = (mat == 0) ? q : (mat == 1) ? k : v;
            long rbase = row0 + mi * 16 + lg * 4;
            #pragma unroll
            for (int j = 0; j < 4; ++j)
                op[(rbase + j) * HDIM + cc] = acc[mi][ni][j];
        }
}

// ---------------------------------------------------------------------------
// Kernel 3: local-window attention.  Window j in [i-16, i] (17 keys).
// Block: 256 threads, 64 rows; thread = (row r = tid>>2, quarter p = tid&3).
// ---------------------------------------------------------------------------
#define DOT4(a, b) ((a).x*(b).x + (a).y*(b).y + (a).z*(b).z + (a).w*(b).w)

__global__ __launch_bounds__(256) void attn_kernel(const float* __restrict__ q,
                                                   const float* __restrict__ k,
                                                   const float* __restrict__ v,
                                                   float* __restrict__ out) {
    __shared__ float Kl[80][68];   // rows r0-16 .. r0+63, pad 68 (272 B, 16B-aligned)
    __shared__ float Vl[80][68];
    __shared__ float Ql[64][68];

    int tid = threadIdx.x;
    int b   = blockIdx.y;
    int r0  = blockIdx.x * 64;
    const float* qb = q + (long)b * T_SEQ * HDIM;
    const float* kb = k + (long)b * T_SEQ * HDIM;
    const float* vb = v + (long)b * T_SEQ * HDIM;

    #pragma unroll
    for (int i = 0; i < 5; ++i) {            // 80 rows * 16 float4 = 1280
        int f = tid + i * 256;
        int r = f >> 4, c = (f & 15) * 4;
        int gr = r0 - 16 + r; if (gr < 0) gr = 0;     // clamped; masked later
        *(float4*)&Kl[r][c] = *(const float4*)(kb + (long)gr * HDIM + c);
        *(float4*)&Vl[r][c] = *(const float4*)(vb + (long)gr * HDIM + c);
    }
    #pragma unroll
    for (int i = 0; i < 4; ++i) {            // 64 rows * 16 float4 = 1024
        int f = tid + i * 256;
        int r = f >> 4, c = (f & 15) * 4;
        *(float4*)&Ql[r][c] = *(const float4*)(qb + (long)(r0 + r) * HDIM + c);
    }
    __syncthreads();

    int r = tid >> 2, p = tid & 3;
    int i_row = r0 + r;                       // row within this batch

    float4 q0 = *(float4*)&Ql[r][p * 16 + 0];
    float4 q1 = *(float4*)&Ql[r][p * 16 + 4];
    float4 q2 = *(float4*)&Ql[r][p * 16 + 8];
    float4 q3 = *(float4*)&Ql[r][p * 16 + 12];

    float s[17];
    float mx = -1e30f;
    #pragma unroll
    for (int jj = 0; jj < 17; ++jj) {
        float d;
        if (i_row - 16 + jj < 0) {
            d = -1e30f;                        // masked (only near batch start)
        } else {
            const float* kr = &Kl[r + jj][p * 16];
            float4 k0 = *(const float4*)(kr + 0);
            float4 k1 = *(const float4*)(kr + 4);
            float4 k2 = *(const float4*)(kr + 8);
            float4 k3 = *(const float4*)(kr + 12);
            float pd = DOT4(q0, k0) + DOT4(q1, k1) + DOT4(q2, k2) + DOT4(q3, k3);
            pd += __shfl_xor(pd, 1, 64);       // quad lanes share a row
            pd += __shfl_xor(pd, 2, 64);
            d = pd * 0.125f;                   // / sqrt(64)
        }
        s[jj] = d;
        mx = fmaxf(mx, d);
    }

    float denom = 0.f;
    float4 o0 = {0,0,0,0}, o1 = {0,0,0,0}, o2 = {0,0,0,0}, o3 = {0,0,0,0};
    #pragma unroll
    for (int jj = 0; jj < 17; ++jj) {
        float wgt = expf(s[jj] - mx);
        denom += wgt;
        const float* vr = &Vl[r + jj][p * 16];
        float4 v0 = *(const float4*)(vr + 0);
        float4 v1 = *(const float4*)(vr + 4);
        float4 v2 = *(const float4*)(vr + 8);
        float4 v3 = *(const float4*)(vr + 12);
        o0.x += wgt * v0.x; o0.y += wgt * v0.y; o0.z += wgt * v0.z; o0.w += wgt * v0.w;
        o1.x += wgt * v1.x; o1.y += wgt * v1.y; o1.z += wgt * v1.z; o1.w += wgt * v1.w;
        o2.x += wgt * v2.x; o2.y += wgt * v2.y; o2.z += wgt * v2.z; o2.w += wgt * v2.w;
        o3.x += wgt * v3.x; o3.y += wgt * v3.y; o3.z += wgt * v3.z; o3.w += wgt * v3.w;
    }
    float inv = 1.f / denom;
    o0.x *= inv; o0.y *= inv; o0.z *= inv; o0.w *= inv;
    o1.x *= inv; o1.y *= inv; o1.z *= inv; o1.w *= inv;
    o2.x *= inv; o2.y *= inv; o2.z *= inv; o2.w *= inv;
    o3.x *= inv; o3.y *= inv; o3.z *= inv; o3.w *= inv;

    float* ob = out + ((long)b * T_SEQ + i_row) * HDIM + p * 16;
    *(float4*)&ob[0]  = o0;
    *(float4*)&ob[4]  = o1;
    *(float4*)&ob[8]  = o2;
    *(float4*)&ob[12] = o3;
}

// ---------------------------------------------------------------------------
extern "C" void kernel_launch(void* const* d_in, const int* in_sizes, int n_in,
                              void* d_out, int out_size, void* d_ws, size_t ws_size,
                              hipStream_t stream) {
    const float* x  = (const float*)d_in[0];
    const float* Wq = (const float*)d_in[1];
    const float* Wk = (const float*)d_in[2];
    const float* Wv = (const float*)d_in[3];
    float* out = (float*)d_out;

    // workspace layout
    unsigned short* WT = (unsigned short*)d_ws;                 // 3*64*1024*2 = 393216 B
    float* qws = (float*)((char*)d_ws + 393216);                // 16384*64*4 each
    float* kws = qws + (long)NROWS * HDIM;
    float* vws = kws + (long)NROWS * HDIM;

    wt_kernel<<<dim3(768), dim3(256), 0, stream>>>(Wq, Wk, Wv, WT);
    qkv_kernel<<<dim3(NROWS / 32), dim3(256), 0, stream>>>(x, WT, qws, kws, vws);
    attn_kernel<<<dim3(T_SEQ / 64, NB), dim3(256), 0, stream>>>(qws, kws, vws, out);
}